// Round 3
// baseline (77.873 us; speedup 1.0000x reference)
//
#include <hip/hip_runtime.h>
#include <stdint.h>

// Problem dims (fixed by reference)
#define D_DIM    768
#define K_STATES 128
#define M_ROWS   65536      // B*T = 256*256
#define BM       64         // rows per block
#define BK       32         // D-chunk per K-step
#define NSTEPS   (D_DIM / BK)   // 24
#define LDSTRIDE 40         // bf16 elems per LDS row: 80B, 16B-aligned, bank-even

typedef __attribute__((ext_vector_type(8))) short bf16x8;
typedef __attribute__((ext_vector_type(4))) float f32x4;
typedef __attribute__((ext_vector_type(4))) int   i32x4;

__device__ __forceinline__ unsigned short f2bf(float f) {
    union { float f; unsigned u; } x; x.f = f;
    unsigned r = (x.u + 0x7FFFu + ((x.u >> 16) & 1u)) >> 16;   // RNE
    return (unsigned short)r;
}

// Single fused kernel: out[bt][k] = cross + c[k] - 0.5*s2[bt]
// Block: 64 rows x 128 states, 4 waves each 32x64 (acc[2][4]), grid = 1024.
// B-tile (means * inv_var -> bf16) converted per-block per-step from f32 means
// (L2-resident, 393KB); m2[k] and sum(log var) computed in-block -> no prep
// kernel, no workspace, no serialized dependent launch.
__global__ void __launch_bounds__(256) dmv_fused(
        const float* __restrict__ s, const float* __restrict__ means,
        const float* __restrict__ var, float* __restrict__ out) {
    __shared__ unsigned short As[2][BM * LDSTRIDE];        // 2 x 5.0 KB
    __shared__ unsigned short Bs[2][K_STATES * LDSTRIDE];  // 2 x 10.0 KB
    __shared__ float ivs[D_DIM];                           // 3 KB
    __shared__ float part[BM][8];                          // s2 partials
    __shared__ float s2row[BM];
    __shared__ float cs[K_STATES];
    __shared__ float rlg[4];

    const int t    = threadIdx.x;
    const int lane = t & 63;
    const int w    = t >> 6;
    const int wr   = w >> 1;      // wave row half (0/1): 32-row halves
    const int wc   = w & 1;       // wave col half (0/1): 64-col halves
    const long rowBase = (long)blockIdx.x * BM;

    // ivs + per-block sum(log var)
    float ldp = 0.f;
    for (int d = t; d < D_DIM; d += 256) {
        float v = var[d];
        ivs[d] = 1.0f / v;
        ldp += logf(v);
    }
#pragma unroll
    for (int off = 32; off > 0; off >>= 1) ldp += __shfl_down(ldp, off, 64);
    if ((t & 63) == 0) rlg[t >> 6] = ldp;

    // staging geometry per K-step:
    // A (64x32 f32): 2 rounds, round j: row = j*32 + (t>>3), cols (t&7)*4 .. +3
    // B (128x32 f32 means): row = t>>1, cols (t&1)*16 + {0,4,8,12}  (16 f32/thread)
    const int arow0 = t >> 3;
    const int acol  = (t & 7) * 4;
    const int brow  = t >> 1;
    const int bcol0 = (t & 1) * 16;

    const float* sA = s     + (rowBase + arow0) * D_DIM + acol;
    const float* sM = means + brow * D_DIM + bcol0;

    f32x4 aPref[2];
    f32x4 bPref[4];
    float s2acc[2] = {0.f, 0.f};
    float m2p = 0.f;

    f32x4 acc[2][4];
#pragma unroll
    for (int i = 0; i < 2; ++i)
#pragma unroll
        for (int j = 0; j < 4; ++j) acc[i][j] = f32x4{0.f, 0.f, 0.f, 0.f};

    auto stageWrite = [&](int buf, int k0) {
        // ---- A: f32 -> bf16 + s2 accumulation
        f32x4 ivv = *reinterpret_cast<const f32x4*>(&ivs[k0 + acol]);
#pragma unroll
        for (int j = 0; j < 2; ++j) {
            const int row = j * 32 + arow0;
            f32x4 v = aPref[j];
            s2acc[j] += v[0]*v[0]*ivv[0] + v[1]*v[1]*ivv[1]
                      + v[2]*v[2]*ivv[2] + v[3]*v[3]*ivv[3];
            unsigned u0 = (unsigned)f2bf(v[0]) | ((unsigned)f2bf(v[1]) << 16);
            unsigned u1 = (unsigned)f2bf(v[2]) | ((unsigned)f2bf(v[3]) << 16);
            *reinterpret_cast<uint2*>(&As[buf][row * LDSTRIDE + acol]) = make_uint2(u0, u1);
        }
        // ---- B: means*iv -> bf16 + m2 accumulation (16 elems/thread)
        f32x4 mw[4];
#pragma unroll
        for (int j = 0; j < 4; ++j) {
            f32x4 iw = *reinterpret_cast<const f32x4*>(&ivs[k0 + bcol0 + j * 4]);
            f32x4 mv = bPref[j];
            m2p += mv[0]*mv[0]*iw[0] + mv[1]*mv[1]*iw[1]
                 + mv[2]*mv[2]*iw[2] + mv[3]*mv[3]*iw[3];
            mw[j] = f32x4{mv[0]*iw[0], mv[1]*iw[1], mv[2]*iw[2], mv[3]*iw[3]};
        }
        i32x4 p0, p1;
        p0.x = (int)((unsigned)f2bf(mw[0][0]) | ((unsigned)f2bf(mw[0][1]) << 16));
        p0.y = (int)((unsigned)f2bf(mw[0][2]) | ((unsigned)f2bf(mw[0][3]) << 16));
        p0.z = (int)((unsigned)f2bf(mw[1][0]) | ((unsigned)f2bf(mw[1][1]) << 16));
        p0.w = (int)((unsigned)f2bf(mw[1][2]) | ((unsigned)f2bf(mw[1][3]) << 16));
        p1.x = (int)((unsigned)f2bf(mw[2][0]) | ((unsigned)f2bf(mw[2][1]) << 16));
        p1.y = (int)((unsigned)f2bf(mw[2][2]) | ((unsigned)f2bf(mw[2][3]) << 16));
        p1.z = (int)((unsigned)f2bf(mw[3][0]) | ((unsigned)f2bf(mw[3][1]) << 16));
        p1.w = (int)((unsigned)f2bf(mw[3][2]) | ((unsigned)f2bf(mw[3][3]) << 16));
        *reinterpret_cast<i32x4*>(&Bs[buf][brow * LDSTRIDE + bcol0])     = p0;
        *reinterpret_cast<i32x4*>(&Bs[buf][brow * LDSTRIDE + bcol0 + 8]) = p1;
    };

    // prologue: global loads for step 0 (no LDS dependence yet)
#pragma unroll
    for (int j = 0; j < 2; ++j)
        aPref[j] = __builtin_nontemporal_load((const f32x4*)(sA + (long)j * 32 * D_DIM));
#pragma unroll
    for (int j = 0; j < 4; ++j)
        bPref[j] = *(const f32x4*)(sM + j * 4);
    __syncthreads();             // ivs / rlg ready
    const float slog = rlg[0] + rlg[1] + rlg[2] + rlg[3];
    stageWrite(0, 0);

    const int g  = (lane >> 4) * 8;          // k-offset within BK
    const int rA = wr * 32 + (lane & 15);
    const int rB = wc * 64 + (lane & 15);

    for (int st = 0; st < NSTEPS; ++st) {
        const int cur = st & 1;
        const int k0n = (st + 1) * BK;
        if (st + 1 < NSTEPS) {
#pragma unroll
            for (int j = 0; j < 2; ++j)
                aPref[j] = __builtin_nontemporal_load(
                               (const f32x4*)(sA + (long)j * 32 * D_DIM + k0n));
#pragma unroll
            for (int j = 0; j < 4; ++j)
                bPref[j] = *(const f32x4*)(sM + k0n + j * 4);
        }
        __syncthreads();         // buf[cur] staged & prior reads drained

        const unsigned short* Ab = &As[cur][0];
        const unsigned short* Bb = &Bs[cur][0];
        bf16x8 afrag[2], bfrag[4];
#pragma unroll
        for (int i = 0; i < 2; ++i)
            afrag[i] = *(const bf16x8*)(Ab + (rA + i * 16) * LDSTRIDE + g);
#pragma unroll
        for (int j = 0; j < 4; ++j)
            bfrag[j] = *(const bf16x8*)(Bb + (rB + j * 16) * LDSTRIDE + g);
#pragma unroll
        for (int i = 0; i < 2; ++i)
#pragma unroll
            for (int j = 0; j < 4; ++j)
                acc[i][j] = __builtin_amdgcn_mfma_f32_16x16x32_bf16(
                                afrag[i], bfrag[j], acc[i][j], 0, 0, 0);

        if (st + 1 < NSTEPS) stageWrite((st + 1) & 1, k0n);
    }

    // s2 partials + per-state constant c[k] = -0.5*(D*log(2pi) + slog + m2[k])
#pragma unroll
    for (int j = 0; j < 2; ++j) part[j * 32 + arow0][t & 7] = s2acc[j];
    {
        float m2t = m2p + __shfl_xor(m2p, 1, 64);   // pair t, t^1 share row brow
        if (!(t & 1))
            cs[brow] = -0.5f * ((float)D_DIM * 1.8378770664093453f + slog + m2t);
    }
    __syncthreads();
    if (t < BM) {
        float v = 0.f;
#pragma unroll
        for (int sl = 0; sl < 8; ++sl) v += part[t][sl];
        s2row[t] = v;
    }
    __syncthreads();

    // epilogue: C/D layout col = lane&15, row = (lane>>4)*4 + reg  [m89/m91-verified]
    const int colBase = wc * 64 + (lane & 15);
#pragma unroll
    for (int i = 0; i < 2; ++i) {
        const int rl0 = wr * 32 + i * 16 + (lane >> 4) * 4;
#pragma unroll
        for (int j = 0; j < 4; ++j) {
            const int col = colBase + j * 16;
            const float cj = cs[col];
#pragma unroll
            for (int r = 0; r < 4; ++r) {
                const int rl = rl0 + r;
                __builtin_nontemporal_store(acc[i][j][r] + cj - 0.5f * s2row[rl],
                                            &out[(rowBase + rl) * K_STATES + col]);
            }
        }
    }
}

extern "C" void kernel_launch(void* const* d_in, const int* in_sizes, int n_in,
                              void* d_out, int out_size, void* d_ws, size_t ws_size,
                              hipStream_t stream) {
    const float* s     = (const float*)d_in[0];
    const float* means = (const float*)d_in[1];
    const float* var   = (const float*)d_in[2];
    float* out = (float*)d_out;

    dmv_fused<<<M_ROWS / BM, 256, 0, stream>>>(s, means, var, out);
}